// Round 1
// baseline (866.330 us; speedup 1.0000x reference)
//
#include <hip/hip_runtime.h>
#include <hip/hip_bf16.h>
#include <string.h>

// Problem constants
#define BB 256
#define NNS 512
#define DDF 128
#define CC1 256
#define CC2 128
#define NPOS (BB * NNS) // 131072

typedef __attribute__((ext_vector_type(4))) float f32x4;
typedef __attribute__((ext_vector_type(8))) short bf16x8;

__device__ __forceinline__ short f2bf(float f) {
    __hip_bfloat16 h = __float2bfloat16(f);
    short s;
    __builtin_memcpy(&s, &h, 2);
    return s;
}
__device__ __forceinline__ float bf2f(short s) {
    unsigned int u = ((unsigned int)(unsigned short)s) << 16;
    float f;
    __builtin_memcpy(&f, &u, 4);
    return f;
}
__device__ __forceinline__ unsigned int pk2bf(float a, float b) {
    float2 t; t.x = a; t.y = b;
    __hip_bfloat162 h = __float22bfloat162_rn(t);
    unsigned int u;
    __builtin_memcpy(&u, &h, 4);
    return u;
}

#define MFMA16(a, b, c) __builtin_amdgcn_mfma_f32_16x16x32_bf16(a, b, c, 0, 0, 0)

// ---------------------------------------------------------------------------
// K0: convert W1/W2 to bf16, zero stat accumulators (ws re-poisoned each call).
__global__ void prep_kernel(const float* __restrict__ W1, const float* __restrict__ W2,
                            short* __restrict__ W1b, short* __restrict__ W2b,
                            float* __restrict__ stats) {
    int idx = blockIdx.x * 256 + threadIdx.x;
    if (idx < CC1 * CC1) W1b[idx] = f2bf(W1[idx]);
    if (idx < CC2 * CC1) W2b[idx] = f2bf(W2[idx]);
    if (idx < 1536) stats[idx] = 0.0f;
}

// ---------------------------------------------------------------------------
// K0b: PT[b][d][j] = bf16(P[b][j][d]). LDS-tiled so reads AND writes coalesce.
// Grid: 2048 = 256 b * 8 j-tiles of 64. Tile: 64 j x 128 d.
__global__ __launch_bounds__(256) void transposeP_kernel(const float* __restrict__ P,
                                                         short* __restrict__ PT) {
    __shared__ float tp[64 * 132]; // pad 132: bank = (j + d) % 32 -> 2-way max
    int b = blockIdx.x >> 3;
    int j0 = (blockIdx.x & 7) * 64;
    int t = threadIdx.x;
    const float* Pb = P + ((size_t)b * NNS + j0) * DDF;
    int jr = t >> 5, dc = (t & 31) * 4;
#pragma unroll
    for (int p = 0; p < 8; ++p) {
        int j = p * 8 + jr;
        float4 v = *reinterpret_cast<const float4*>(&Pb[(size_t)j * DDF + dc]);
        *reinterpret_cast<float4*>(&tp[j * 132 + dc]) = v;
    }
    __syncthreads();
    int jo = t & 7;
#pragma unroll
    for (int p = 0; p < 4; ++p) {
        int d = p * 32 + (t >> 3);
        bf16x8 v;
#pragma unroll
        for (int s = 0; s < 8; ++s) v[s] = f2bf(tp[(jo * 8 + s) * 132 + d]);
        *reinterpret_cast<bf16x8*>(&PT[((size_t)(b * DDF + d)) * NNS + j0 + jo * 8]) = v;
    }
}

// ---------------------------------------------------------------------------
// K1: masked + L1-normalized edge aggregation.
//   X[b][i][e*128+d] = (1/max(sum_j |E~[i,j]|, eps)) * sum_j E~[i,j]*P[j,d]
// Direct global->reg streaming GEMM: NO LDS, NO barriers. Each wave owns a
// distinct 32-row x 128-col tile (A read exactly once; B is L1/L2-hot PT).
// A is depth-1 prefetched in registers; diag mask hits exactly one kk
// (wave-uniform branch). Mask -> |row sum| -> bf16 pack fused on the reg path.
__global__ __launch_bounds__(256) void gemm1_kernel(const float* __restrict__ dE,
                                                    const float* __restrict__ iE,
                                                    const short* __restrict__ PT,
                                                    short* __restrict__ X) {
    int bid = blockIdx.x; // 2048 = 256 b * 2 e * 4 mtiles
    int mtb = bid & 3;
    int e = (bid >> 2) & 1;
    int b = bid >> 3;
    const float* E = (e == 0 ? dE : iE) + (size_t)b * (NNS * NNS);
    const short* PTb = PT + (size_t)b * (DDF * NNS);

    int tid = threadIdx.x;
    int lane = tid & 63, w = tid >> 6;
    int quad = lane >> 4, lr = lane & 15;
    int rbase = mtb * 128 + w * 32; // wave's 32-row slice (distinct per wave)

    const float* Ap[2];
#pragma unroll
    for (int mt = 0; mt < 2; ++mt)
        Ap[mt] = E + (size_t)(rbase + mt * 16 + lr) * NNS + quad * 8;
    const short* Bp[8];
#pragma unroll
    for (int nt = 0; nt < 8; ++nt)
        Bp[nt] = PTb + (size_t)(nt * 16 + lr) * NNS + quad * 8;

    f32x4 zero = {0.f, 0.f, 0.f, 0.f};
    f32x4 acc[2][8];
#pragma unroll
    for (int a = 0; a < 2; ++a)
#pragma unroll
        for (int c = 0; c < 8; ++c) acc[a][c] = zero;
    float rs[2] = {0.f, 0.f};

    // depth-1 A prefetch (HBM stream); B loaded in-iteration (cache-hot)
    float4 pa0[2], pa1[2];
#pragma unroll
    for (int mt = 0; mt < 2; ++mt) {
        pa0[mt] = *reinterpret_cast<const float4*>(Ap[mt]);
        pa1[mt] = *reinterpret_cast<const float4*>(Ap[mt] + 4);
    }
    int kkd = rbase >> 5; // only kk where the diagonal can fall in this tile

#pragma unroll 2
    for (int kk = 0; kk < 16; ++kk) {
        bf16x8 bv[8];
#pragma unroll
        for (int nt = 0; nt < 8; ++nt)
            bv[nt] = *reinterpret_cast<const bf16x8*>(Bp[nt] + kk * 32);
#pragma unroll
        for (int mt = 0; mt < 2; ++mt) {
            float4 v0 = pa0[mt], v1 = pa1[mt];
            if (kk < 15) {
                pa0[mt] = *reinterpret_cast<const float4*>(Ap[mt] + (kk + 1) * 32);
                pa1[mt] = *reinterpret_cast<const float4*>(Ap[mt] + (kk + 1) * 32 + 4);
            }
            float a8[8] = {v0.x, v0.y, v0.z, v0.w, v1.x, v1.y, v1.z, v1.w};
            if (kk == kkd) { // wave-uniform: rows [rbase+mt*16, +16) in this k-window
                int t = (mt << 4) + lr;
#pragma unroll
                for (int tt = 0; tt < 8; ++tt)
                    if (quad * 8 + tt == t) a8[tt] = 0.0f; // diag mask
            }
            float s = rs[mt];
#pragma unroll
            for (int tt = 0; tt < 8; ++tt) s += fabsf(a8[tt]); // L1 row sum
            rs[mt] = s;
            union { bf16x8 v; unsigned int u[4]; } af;
#pragma unroll
            for (int tt = 0; tt < 4; ++tt) af.u[tt] = pk2bf(a8[2 * tt], a8[2 * tt + 1]);
#pragma unroll
            for (int nt = 0; nt < 8; ++nt)
                acc[mt][nt] = MFMA16(af.v, bv[nt], acc[mt][nt]);
        }
    }

    // full row sums: combine the 4 k-octet partials (quads), then scale+store
#pragma unroll
    for (int mt = 0; mt < 2; ++mt) {
        float s = rs[mt];
        s += __shfl_xor(s, 16, 64);
        s += __shfl_xor(s, 32, 64);
        float inv = 1.0f / fmaxf(s, 1e-12f);
        float ir[4];
#pragma unroll
        for (int r = 0; r < 4; ++r) ir[r] = __shfl(inv, quad * 4 + r, 64);
#pragma unroll
        for (int nt = 0; nt < 8; ++nt) {
            int col = e * 128 + nt * 16 + lr;
#pragma unroll
            for (int r = 0; r < 4; ++r) {
                int row = rbase + mt * 16 + quad * 4 + r;
                X[((size_t)b * NNS + row) * CC1 + col] = f2bf(acc[mt][nt][r] * ir[r]);
            }
        }
    }
}

// ---------------------------------------------------------------------------
// K2: Y1[pos][o] = sum_c X[pos][c]*W1[o][c]; BN1 stats. Direct global->reg,
// no LDS/barriers. 512 thr: 8 waves (mh 2 x nh 4), tile 128 pos x 256 o.
__global__ __launch_bounds__(512) void gemm2_kernel(const short* __restrict__ X,
                                                    const short* __restrict__ W1b,
                                                    short* __restrict__ Y1,
                                                    float* __restrict__ sum1,
                                                    float* __restrict__ sumsq1) {
    int pbase = blockIdx.x * 128; // 1024 blocks
    int tid = threadIdx.x;
    int lane = tid & 63, w = tid >> 6;
    int quad = lane >> 4, lr = lane & 15;
    int mh = w >> 2, nh = w & 3;

    const short* Ap[4];
#pragma unroll
    for (int mt = 0; mt < 4; ++mt)
        Ap[mt] = X + (size_t)(pbase + mh * 64 + mt * 16 + lr) * CC1 + quad * 8;
    const short* Bp[4];
#pragma unroll
    for (int nt = 0; nt < 4; ++nt)
        Bp[nt] = W1b + (size_t)(nh * 64 + nt * 16 + lr) * CC1 + quad * 8;

    f32x4 zero = {0.f, 0.f, 0.f, 0.f};
    f32x4 acc[4][4];
#pragma unroll
    for (int a = 0; a < 4; ++a)
#pragma unroll
        for (int c = 0; c < 4; ++c) acc[a][c] = zero;

    bf16x8 pa[4];
#pragma unroll
    for (int mt = 0; mt < 4; ++mt) pa[mt] = *reinterpret_cast<const bf16x8*>(Ap[mt]);

#pragma unroll 2
    for (int kk = 0; kk < 8; ++kk) {
        bf16x8 bv[4];
#pragma unroll
        for (int nt = 0; nt < 4; ++nt)
            bv[nt] = *reinterpret_cast<const bf16x8*>(Bp[nt] + kk * 32);
#pragma unroll
        for (int mt = 0; mt < 4; ++mt) {
            bf16x8 av = pa[mt];
            if (kk < 7) pa[mt] = *reinterpret_cast<const bf16x8*>(Ap[mt] + (kk + 1) * 32);
#pragma unroll
            for (int nt = 0; nt < 4; ++nt) acc[mt][nt] = MFMA16(av, bv[nt], acc[mt][nt]);
        }
    }
#pragma unroll
    for (int nt = 0; nt < 4; ++nt) {
        int o = nh * 64 + nt * 16 + lr;
        float s = 0.f, q = 0.f;
#pragma unroll
        for (int mt = 0; mt < 4; ++mt)
#pragma unroll
            for (int r = 0; r < 4; ++r) {
                float v = acc[mt][nt][r];
                s += v;
                q += v * v;
            }
        s += __shfl_xor(s, 16, 64); s += __shfl_xor(s, 32, 64);
        q += __shfl_xor(q, 16, 64); q += __shfl_xor(q, 32, 64);
        if (lane < 16) {
            atomicAdd(&sum1[o], s);
            atomicAdd(&sumsq1[o], q);
        }
#pragma unroll
        for (int mt = 0; mt < 4; ++mt)
#pragma unroll
            for (int r = 0; r < 4; ++r) {
                int pos = pbase + mh * 64 + mt * 16 + quad * 4 + r;
                Y1[(size_t)pos * CC1 + o] = f2bf(acc[mt][nt][r]);
            }
    }
}

// ---------------------------------------------------------------------------
// BN finalize: scale = g*rsqrt(var+eps), shift = b - mean*scale
__global__ void finalize_kernel(const float* __restrict__ sum, const float* __restrict__ sumsq,
                                const float* __restrict__ g, const float* __restrict__ b,
                                float* __restrict__ scale, float* __restrict__ shift, int C) {
    int i = threadIdx.x;
    if (i < C) {
        const float invM = 1.0f / (float)NPOS;
        float m = sum[i] * invM;
        float v = sumsq[i] * invM - m * m;
        float s = g[i] * rsqrtf(v + 1e-5f);
        scale[i] = s;
        shift[i] = b[i] - m * s;
    }
}

// ---------------------------------------------------------------------------
// K3: Y2[pos][o] = sum_c lrelu(bn1(Y1[pos][c]))*W2[o][c]; BN2 stats.
// Direct global->reg; BN1+lrelu fused on the A reg path. 256 thr, 4 waves.
__global__ __launch_bounds__(256) void gemm3_kernel(const short* __restrict__ Y1,
                                                    const short* __restrict__ W2b,
                                                    const float* __restrict__ scale1,
                                                    const float* __restrict__ shift1,
                                                    float* __restrict__ Y2,
                                                    float* __restrict__ sum2,
                                                    float* __restrict__ sumsq2) {
    __shared__ __align__(16) float ssc[CC1];
    __shared__ __align__(16) float ssh[CC1];
    ssc[threadIdx.x] = scale1[threadIdx.x];
    ssh[threadIdx.x] = shift1[threadIdx.x];
    __syncthreads();

    int pbase = blockIdx.x * 128; // 1024 blocks
    int tid = threadIdx.x;
    int lane = tid & 63, w = tid >> 6;
    int quad = lane >> 4, lr = lane & 15;
    int mh = w >> 1, nh = w & 1;

    const short* Ap[4];
#pragma unroll
    for (int mt = 0; mt < 4; ++mt)
        Ap[mt] = Y1 + (size_t)(pbase + mh * 64 + mt * 16 + lr) * CC1 + quad * 8;
    const short* Bp[4];
#pragma unroll
    for (int nt = 0; nt < 4; ++nt)
        Bp[nt] = W2b + (size_t)(nh * 64 + nt * 16 + lr) * CC1 + quad * 8;

    f32x4 zero = {0.f, 0.f, 0.f, 0.f};
    f32x4 acc[4][4];
#pragma unroll
    for (int a = 0; a < 4; ++a)
#pragma unroll
        for (int c = 0; c < 4; ++c) acc[a][c] = zero;

    bf16x8 pa[4];
#pragma unroll
    for (int mt = 0; mt < 4; ++mt) pa[mt] = *reinterpret_cast<const bf16x8*>(Ap[mt]);

#pragma unroll 2
    for (int kk = 0; kk < 8; ++kk) {
        bf16x8 bv[4];
#pragma unroll
        for (int nt = 0; nt < 4; ++nt)
            bv[nt] = *reinterpret_cast<const bf16x8*>(Bp[nt] + kk * 32);
        int k0 = kk * 32 + quad * 8;
        float4 sc0 = *reinterpret_cast<const float4*>(&ssc[k0]);
        float4 sc1 = *reinterpret_cast<const float4*>(&ssc[k0 + 4]);
        float4 sh0 = *reinterpret_cast<const float4*>(&ssh[k0]);
        float4 sh1 = *reinterpret_cast<const float4*>(&ssh[k0 + 4]);
        float scv[8] = {sc0.x, sc0.y, sc0.z, sc0.w, sc1.x, sc1.y, sc1.z, sc1.w};
        float shv[8] = {sh0.x, sh0.y, sh0.z, sh0.w, sh1.x, sh1.y, sh1.z, sh1.w};
#pragma unroll
        for (int mt = 0; mt < 4; ++mt) {
            bf16x8 raw = pa[mt];
            if (kk < 7) pa[mt] = *reinterpret_cast<const bf16x8*>(Ap[mt] + (kk + 1) * 32);
            union { bf16x8 v; unsigned int u[4]; } af;
#pragma unroll
            for (int tt = 0; tt < 4; ++tt) {
                float va = bf2f(raw[2 * tt]) * scv[2 * tt] + shv[2 * tt];
                va = fmaxf(va, 0.01f * va);
                float vb = bf2f(raw[2 * tt + 1]) * scv[2 * tt + 1] + shv[2 * tt + 1];
                vb = fmaxf(vb, 0.01f * vb);
                af.u[tt] = pk2bf(va, vb);
            }
#pragma unroll
            for (int nt = 0; nt < 4; ++nt) acc[mt][nt] = MFMA16(af.v, bv[nt], acc[mt][nt]);
        }
    }
#pragma unroll
    for (int nt = 0; nt < 4; ++nt) {
        int o = nh * 64 + nt * 16 + lr;
        float s = 0.f, q = 0.f;
#pragma unroll
        for (int mt = 0; mt < 4; ++mt)
#pragma unroll
            for (int r = 0; r < 4; ++r) {
                float v = acc[mt][nt][r];
                s += v;
                q += v * v;
            }
        s += __shfl_xor(s, 16, 64); s += __shfl_xor(s, 32, 64);
        q += __shfl_xor(q, 16, 64); q += __shfl_xor(q, 32, 64);
        if (lane < 16) {
            atomicAdd(&sum2[o], s);
            atomicAdd(&sumsq2[o], q);
        }
#pragma unroll
        for (int mt = 0; mt < 4; ++mt)
#pragma unroll
            for (int r = 0; r < 4; ++r) {
                int pos = pbase + mh * 64 + mt * 16 + quad * 4 + r;
                Y2[(size_t)pos * CC2 + o] = acc[mt][nt][r];
            }
    }
}

// ---------------------------------------------------------------------------
// K4: out = lrelu(bn2(Y2)), fp32, (B,N,128) layout.
__global__ void apply2_kernel(const float* __restrict__ Y2, const float* __restrict__ scale2,
                              const float* __restrict__ shift2, float* __restrict__ out) {
    size_t gid = (size_t)blockIdx.x * 256 + threadIdx.x;
    size_t base = gid * 4;
    float4 y = *reinterpret_cast<const float4*>(&Y2[base]);
    int o = (int)(base & 127);
    float4 sc = *reinterpret_cast<const float4*>(&scale2[o]);
    float4 sh = *reinterpret_cast<const float4*>(&shift2[o]);
    float4 t;
    t.x = y.x * sc.x + sh.x; t.x = fmaxf(t.x, 0.01f * t.x);
    t.y = y.y * sc.y + sh.y; t.y = fmaxf(t.y, 0.01f * t.y);
    t.z = y.z * sc.z + sh.z; t.z = fmaxf(t.z, 0.01f * t.z);
    t.w = y.w * sc.w + sh.w; t.w = fmaxf(t.w, 0.01f * t.w);
    *reinterpret_cast<float4*>(&out[base]) = t;
}

// ---------------------------------------------------------------------------
extern "C" void kernel_launch(void* const* d_in, const int* in_sizes, int n_in,
                              void* d_out, int out_size, void* d_ws, size_t ws_size,
                              hipStream_t stream) {
    const float* dE = (const float*)d_in[0];
    const float* iE = (const float*)d_in[1];
    const float* P  = (const float*)d_in[2];
    const float* W1 = (const float*)d_in[3];
    const float* g1 = (const float*)d_in[4];
    const float* b1 = (const float*)d_in[5];
    const float* W2 = (const float*)d_in[6];
    const float* g2 = (const float*)d_in[7];
    const float* b2 = (const float*)d_in[8];
    float* out = (float*)d_out;
    char* ws = (char*)d_ws;

    // Workspace layout (~160.2 MiB total):
    short* PT  = (short*)(ws + 0);           // 32 MiB  bf16 P^T [b][d][j]
    short* X   = (short*)(ws + 33554432);    // 64 MiB  bf16 aggr concat [pos][256]
    short* Y1  = (short*)(ws + 100663296);   // 64 MiB  bf16 conv1 raw  [pos][256]
    float* Y2  = (float*)(ws + 33554432);    // 64 MiB  fp32 conv2 raw  [pos][128] (aliases dead X)
    short* W1b = (short*)(ws + 167772160);   // 128 KiB
    short* W2b = (short*)(ws + 167903232);   // 64 KiB
    float* st  = (float*)(ws + 167968768);   // 6 KiB stats
    float* sum1 = st,        * sumsq1 = st + 256, * scale1 = st + 512,  * shift1 = st + 768;
    float* sum2 = st + 1024, * sumsq2 = st + 1152, * scale2 = st + 1280, * shift2 = st + 1408;

    prep_kernel<<<256, 256, 0, stream>>>(W1, W2, W1b, W2b, st);
    transposeP_kernel<<<2048, 256, 0, stream>>>(P, PT);
    gemm1_kernel<<<2048, 256, 0, stream>>>(dE, iE, PT, X);
    gemm2_kernel<<<1024, 512, 0, stream>>>(X, W1b, Y1, sum1, sumsq1);
    finalize_kernel<<<1, 256, 0, stream>>>(sum1, sumsq1, g1, b1, scale1, shift1, CC1);
    gemm3_kernel<<<1024, 256, 0, stream>>>(Y1, W2b, scale1, shift1, Y2, sum2, sumsq2);
    finalize_kernel<<<1, 128, 0, stream>>>(sum2, sumsq2, g2, b2, scale2, shift2, CC2);
    apply2_kernel<<<16384, 256, 0, stream>>>(Y2, scale2, shift2, out);
}